// Round 1
// 360.705 us; speedup vs baseline: 1.0591x; 1.0591x over previous
//
#include <hip/hip_runtime.h>
#include <math.h>

#define Nn 4096
#define Ee 32768
#define Bb 64
#define FINc 128
#define Dd 64
#define SIGf 0.15f
#define LAMf 0.01f
#define EPSf 1e-5f

typedef __attribute__((ext_vector_type(8))) short bf16x8;
typedef __attribute__((ext_vector_type(4))) float f32x4;

__device__ inline short f2bf(float f) {
  union { float f; unsigned u; } v; v.f = f;
  unsigned r = v.u + 0x7fffu + ((v.u >> 16) & 1u);
  return (short)(r >> 16);
}
__device__ inline bf16x8 pack8v(f32x4 a, f32x4 b) {
  bf16x8 r;
  r[0]=f2bf(a.x); r[1]=f2bf(a.y); r[2]=f2bf(a.z); r[3]=f2bf(a.w);
  r[4]=f2bf(b.x); r[5]=f2bf(b.y); r[6]=f2bf(b.z); r[7]=f2bf(b.w);
  return r;
}
__device__ inline float sigm(float x) { return 1.f / (1.f + expf(-x)); }

// ---------------- tkl (output element 64) ----------------
__global__ void k_tkl(const float* __restrict__ preW, const float* __restrict__ preb,
                      const float* __restrict__ postW, const float* __restrict__ postb,
                      const float* __restrict__ outW, const float* __restrict__ outb,
                      float* __restrict__ y) {
  int tid = threadIdx.x;
  const float logc = logf(SIGf * sqrtf(6.28318530717958647692f));
  const float c2 = 0.5f / (SIGf * SIGf);
  float acc = 0.f;
  for (int i = tid; i < FINc*Dd; i += 256) { float w = preW[i];  acc += c2*w*w + logc; }
  for (int i = tid; i < Dd; i += 256)      { float w = preb[i];  acc += c2*w*w + logc; }
  for (int i = tid; i < Dd*Dd; i += 256)   { float w = postW[i]; acc += c2*w*w + logc; }
  for (int i = tid; i < Dd; i += 256)      { float w = postb[i]; acc += c2*w*w + logc; }
  for (int i = tid; i < Dd; i += 256)      { float w = outW[i];  acc += c2*w*w + logc; }
  if (tid == 0)                            { float w = outb[0];  acc += c2*w*w + logc; }
  __shared__ float red[256];
  red[tid] = acc; __syncthreads();
  for (int s = 128; s > 0; s >>= 1) { if (tid < s) red[tid] += red[tid+s]; __syncthreads(); }
  if (tid == 0) y[Bb] = red[0];
}

// ---------------- count in-degree ----------------
__global__ void k_count(const int* __restrict__ dst, float* __restrict__ cnt) {
  int e = blockIdx.x * 256 + threadIdx.x;
  if (e < Ee) atomicAdd(&cnt[dst[e]], 1.0f);
}

// ---------------- weight prep: bf16 packs/transposes ----------------
__global__ void k_prep(const float* __restrict__ w1, const float* __restrict__ w2,
                       const float* __restrict__ b2, const float* __restrict__ rootw,
                       const float* __restrict__ gwih, const float* __restrict__ gwhh,
                       const float* __restrict__ preW,
                       short* __restrict__ w1T, short* __restrict__ b2T,
                       short* __restrict__ w2T, short* __restrict__ rootwT,
                       short* __restrict__ gwihB, short* __restrict__ gwhhB,
                       short* __restrict__ preWT) {
  int idx = blockIdx.x * 256 + threadIdx.x;
  if (idx < 3*64*64*64) {
    int f = idx & 63, o = (idx >> 6) & 63, h = (idx >> 12) & 63, l = idx >> 18;
    w2T[idx] = f2bf(w2[(((l*64 + h)*64 + f) << 6) + o]);
  }
  if (idx < 3*64*64) {
    int f = idx & 63, h = (idx >> 6) & 63, l = idx >> 12;
    w1T[idx] = f2bf(w1[l*4096 + f*64 + h]);
    b2T[idx] = f2bf(b2[l*4096 + f*64 + h]);
    rootwT[idx] = f2bf(rootw[l*4096 + f*64 + h]);  // rootwT[l][d][k] = rootw[l][k][d]
  }
  if (idx < 3*192*64) {
    gwihB[idx] = f2bf(gwih[idx]);
    gwhhB[idx] = f2bf(gwhh[idx]);
  }
  if (idx < 64*128) {
    int k = idx & 127, d = idx >> 7;
    preWT[idx] = f2bf(preW[k*64 + d]);             // preWT[d][k]
  }
}

// ---------------- pre FC + relu via MFMA: out = relu(x @ preW + preb) ----------------
__global__ __launch_bounds__(256) void k_pre(const float* __restrict__ x,
                                             const short* __restrict__ preWT,
                                             const float* __restrict__ preb,
                                             float* __restrict__ out, float* __restrict__ h) {
  const int tid = threadIdx.x, lane = tid & 63, wave = tid >> 6;
  const int m15 = lane & 15, kq = lane >> 4;
  const int nb = blockIdx.x * 16;
  const f32x4 zero4 = {0.f,0.f,0.f,0.f};
  const int d = wave*16 + m15;
  bf16x8 bfr[4];
  #pragma unroll
  for (int c = 0; c < 4; ++c)
    bfr[c] = *(const bf16x8*)(preWT + d*128 + c*32 + kq*8);
  const float* xp = x + (size_t)(nb + m15)*128 + kq*8;
  f32x4 p = zero4;
  #pragma unroll
  for (int c = 0; c < 4; ++c) {
    bf16x8 a = pack8v(*(const f32x4*)(xp + c*32), *(const f32x4*)(xp + c*32 + 4));
    p = __builtin_amdgcn_mfma_f32_16x16x32_bf16(a, bfr[c], p, 0, 0, 0);
  }
  float bv = preb[d];
  #pragma unroll
  for (int r = 0; r < 4; ++r) {
    int node = nb + kq*4 + r;
    float v = fmaxf(p[r] + bv, 0.f);
    out[node*64 + d] = v;
    h[node*64 + d] = v;
  }
}

// ---------------- fused edge-MLP + bilinear message GEMM (MFMA) + scatter ----------------
// 128 edges per block, 8 waves: wave = (eh<<2)|ow; eh = edge half, ow = o-slice.
// Wave pairs (eh=0/1, same ow) read identical w2 rows -> L1/L2 broadcast.
// 4-stage register prefetch (A/B/C/D, reload-after-use, no rotation copies)
// gives ~3 compute-phases of load->use slack (8 loads in flight / wave).
#define MSG_PHASE(W0, W1, hh)                                                              \
  {                                                                                        \
    _Pragma("unroll")                                                                      \
    for (int t = 0; t < 4; ++t) {                                                          \
      f32x4 p = __builtin_amdgcn_mfma_f32_16x16x32_bf16(sfrag[t][0], W0, zero4, 0, 0, 0);  \
      p = __builtin_amdgcn_mfma_f32_16x16x32_bf16(sfrag[t][1], W1, p, 0, 0, 0);            \
      f32x4 hv = *(const f32x4*)(hidT + (hh)*132 + ehb + t*16 + kq*4);                     \
      acc[t] += hv * p;                                                                    \
    }                                                                                      \
  }
#define MSG_RELOAD(W0, W1, hh)                                                             \
  {                                                                                        \
    const short* fp_ = ((hh) < 64) ? (w2base + (size_t)(hh)*4096) : b2base;                \
    W0 = *(const bf16x8*)(fp_);                                                            \
    W1 = *(const bf16x8*)(fp_ + 32);                                                       \
  }

__global__ __launch_bounds__(512) void k_msg(
    const float* __restrict__ out, const float* __restrict__ edge_attr,
    const short* __restrict__ w1T, const float* __restrict__ b1,
    const short* __restrict__ w2T, const short* __restrict__ b2T,
    const int* __restrict__ src, const int* __restrict__ dst,
    float* __restrict__ agg) {
  __shared__ __align__(16) float hidT[64*132];   // [h][edge], pad 128->132
  __shared__ int srcv[128];
  __shared__ int dstv[128];

  const int tid  = threadIdx.x;
  const int lane = tid & 63;
  const int wave = tid >> 6;      // 0..7
  const int eh   = wave >> 2;     // edge half 0/1
  const int ow   = wave & 3;      // o-slice
  const int m15  = lane & 15;
  const int kq   = lane >> 4;
  const int ehb  = eh*64;
  const int ebase = blockIdx.x * 128;

  if (tid < 128) { srcv[tid] = src[ebase + tid]; dstv[tid] = dst[ebase + tid]; }
  __syncthreads();

  const f32x4 zero4 = {0.f, 0.f, 0.f, 0.f};

  // gather source-node features for this wave's 64-edge half
  bf16x8 sfrag[4][2];
  #pragma unroll
  for (int t = 0; t < 4; ++t) {
    int node = srcv[ehb + t*16 + m15];
    const float* sp = out + node*64 + kq*8;
    #pragma unroll
    for (int ks = 0; ks < 2; ++ks) {
      f32x4 a = *(const f32x4*)(sp + ks*32);
      f32x4 b = *(const f32x4*)(sp + ks*32 + 4);
      sfrag[t][ks] = pack8v(a, b);
    }
  }

  // edge MLP layer 1: hid[h = ow*16+m15][edges of this half]
  {
    const short* wp = w1T + (ow*16 + m15)*64 + kq*8;
    bf16x8 bw0 = *(const bf16x8*)(wp);
    bf16x8 bw1 = *(const bf16x8*)(wp + 32);
    float b1v = b1[ow*16 + m15];
    #pragma unroll
    for (int t = 0; t < 4; ++t) {
      const float* ep = edge_attr + (size_t)(ebase + ehb + t*16 + m15)*64 + kq*8;
      bf16x8 a0 = pack8v(*(const f32x4*)(ep),      *(const f32x4*)(ep + 4));
      bf16x8 a1 = pack8v(*(const f32x4*)(ep + 32), *(const f32x4*)(ep + 36));
      f32x4 p = __builtin_amdgcn_mfma_f32_16x16x32_bf16(a0, bw0, zero4, 0, 0, 0);
      p = __builtin_amdgcn_mfma_f32_16x16x32_bf16(a1, bw1, p, 0, 0, 0);
      f32x4 v;
      v.x = fmaxf(p.x + b1v, 0.f); v.y = fmaxf(p.y + b1v, 0.f);
      v.z = fmaxf(p.z + b1v, 0.f); v.w = fmaxf(p.w + b1v, 0.f);
      *(f32x4*)(hidT + (ow*16 + m15)*132 + ehb + t*16 + kq*4) = v;
    }
  }
  __syncthreads();

  f32x4 acc[4] = {zero4, zero4, zero4, zero4};
  const short* w2base = w2T + (ow*16 + m15)*64 + kq*8;
  const short* b2base = b2T + (ow*16 + m15)*64 + kq*8;

  bf16x8 A0, A1, B0, B1, C0, C1, D0, D1;
  MSG_RELOAD(A0, A1, 0)
  MSG_RELOAD(B0, B1, 1)
  MSG_RELOAD(C0, C1, 2)
  MSG_RELOAD(D0, D1, 3)
  for (int h = 0; h < 64; h += 4) {
    MSG_PHASE(A0, A1, h)     MSG_RELOAD(A0, A1, h + 4)
    MSG_PHASE(B0, B1, h + 1) MSG_RELOAD(B0, B1, h + 5)
    MSG_PHASE(C0, C1, h + 2) MSG_RELOAD(C0, C1, h + 6)
    MSG_PHASE(D0, D1, h + 3) MSG_RELOAD(D0, D1, h + 7)
  }
  // bias row (b2) sits in A0/A1 (prefetched at h=60 with hh=64)
  #pragma unroll
  for (int t = 0; t < 4; ++t) {
    f32x4 p = __builtin_amdgcn_mfma_f32_16x16x32_bf16(sfrag[t][0], A0, zero4, 0, 0, 0);
    p = __builtin_amdgcn_mfma_f32_16x16x32_bf16(sfrag[t][1], A1, p, 0, 0, 0);
    acc[t] += p;
  }

  const int o = ow*16 + m15;
  #pragma unroll
  for (int t = 0; t < 4; ++t) {
    #pragma unroll
    for (int r = 0; r < 4; ++r) {
      int e = ehb + t*16 + kq*4 + r;
      atomicAdd(&agg[dstv[e]*64 + o], acc[t][r]);
    }
  }
}

// ---------------- fused: m = agg/cnt + out@rootw + rootb ; softmax ; BN stats ----------------
// 16 nodes per block -> grid 256 (was 64; only 25% of CUs were used)
__global__ __launch_bounds__(256) void k_m_fused(
    const float* __restrict__ agg, const float* __restrict__ cnt,
    const float* __restrict__ out, const short* __restrict__ rootwT,
    const float* __restrict__ rootb, const float* __restrict__ gnlin,
    float* __restrict__ m, float* __restrict__ sbuf, float* __restrict__ stats) {
  __shared__ float msh[16*65];
  __shared__ float lgsh[16*12];
  __shared__ float ssh[16*16];
  const int tid = threadIdx.x, lane = tid & 63, wave = tid >> 6;
  const int m15 = lane & 15, kq = lane >> 4;
  const int nb = blockIdx.x * 16;
  const f32x4 zero4 = {0.f,0.f,0.f,0.f};
  const int d = wave*16 + m15;

  bf16x8 b0 = *(const bf16x8*)(rootwT + d*64 + kq*8);
  bf16x8 b1 = *(const bf16x8*)(rootwT + d*64 + 32 + kq*8);
  float rbv = rootb[d];
  {
    const float* sp = out + (size_t)(nb + m15)*64 + kq*8;
    bf16x8 a0 = pack8v(*(const f32x4*)(sp),      *(const f32x4*)(sp + 4));
    bf16x8 a1 = pack8v(*(const f32x4*)(sp + 32), *(const f32x4*)(sp + 36));
    f32x4 p = __builtin_amdgcn_mfma_f32_16x16x32_bf16(a0, b0, zero4, 0, 0, 0);
    p = __builtin_amdgcn_mfma_f32_16x16x32_bf16(a1, b1, p, 0, 0, 0);
    #pragma unroll
    for (int r = 0; r < 4; ++r) {
      int ln = kq*4 + r;
      int node = nb + ln;
      float mv = agg[node*64 + d] / fmaxf(cnt[node], 1.f) + rbv + p[r];
      m[node*64 + d] = mv;
      msh[ln*65 + d] = mv;
    }
  }
  __syncthreads();

  // logits: 16 nodes x 10 groups
  {
    int n = tid >> 4, g = tid & 15;
    if (g < 10) {
      float lg = 0.f;
      #pragma unroll 8
      for (int k = 0; k < 64; ++k) lg += msh[n*65 + k] * gnlin[k*10 + g];
      lgsh[n*12 + g] = lg;
    }
  }
  __syncthreads();
  // softmax
  {
    int n = tid >> 4, g = tid & 15;
    if (g < 10) {
      float mx = -1e30f;
      #pragma unroll
      for (int gg = 0; gg < 10; ++gg) mx = fmaxf(mx, lgsh[n*12 + gg]);
      float sum = 0.f;
      #pragma unroll
      for (int gg = 0; gg < 10; ++gg) sum += expf(lgsh[n*12 + gg] - mx);
      float sv = expf(lgsh[n*12 + g] - mx) / sum;
      sbuf[(nb + n)*16 + g] = sv;
      ssh[n*16 + g] = sv;
    }
  }
  __syncthreads();
  // BN stat partials over this block's 16 nodes
  for (int c = tid; c < 640; c += 256) {
    int g = c >> 6, dd = c & 63;
    float a1 = 0.f, a2 = 0.f;
    #pragma unroll
    for (int n = 0; n < 16; ++n) {
      float t = ssh[n*16 + g] * msh[n*65 + dd];
      a1 += t; a2 += t*t;
    }
    atomicAdd(&stats[c], a1);
    atomicAdd(&stats[640 + c], a2);
  }
}

// ---------------- fused DGN-finalize + relu + GRU (MFMA) + residual ----------------
// 16 nodes per block -> grid 256 (was 128)
__global__ __launch_bounds__(256) void k_gru(
    const float* __restrict__ m, const float* __restrict__ sbuf,
    const float* __restrict__ stats, const float* __restrict__ gamma,
    const float* __restrict__ beta, const short* __restrict__ gwihB,
    const short* __restrict__ gwhhB, const float* __restrict__ bih,
    const float* __restrict__ bhh, float* __restrict__ h,
    float* __restrict__ out) {
  __shared__ __align__(16) float mrsh[16*68];
  __shared__ float igsh[640];
  __shared__ float Bsh[64];
  __shared__ float ssh[256];
  const int tid = threadIdx.x, lane = tid & 63, wave = tid >> 6;
  const int m15 = lane & 15, kq = lane >> 4;
  const int nb = blockIdx.x * 16;
  const f32x4 zero4 = {0.f,0.f,0.f,0.f};
  const float invN = 1.f / (float)Nn;

  if (tid < 64) {
    float bacc = 0.f;
    #pragma unroll
    for (int g = 0; g < 10; ++g) {
      int c = g*64 + tid;
      float mu = stats[c] * invN;
      float var = stats[640 + c] * invN - mu*mu;
      float ig = (1.0f / sqrtf(var + EPSf)) * gamma[c];
      igsh[c] = ig;
      bacc += beta[c] - mu * ig;
    }
    Bsh[tid] = bacc;
  }
  ssh[tid] = sbuf[nb*16 + tid];
  __syncthreads();

  for (int idx = tid; idx < 1024; idx += 256) {
    int n = idx >> 6, dd = idx & 63;
    float mv = m[(nb + n)*64 + dd];
    float SA = 0.f;
    #pragma unroll
    for (int g = 0; g < 10; ++g) SA += ssh[n*16 + g] * igsh[g*64 + dd];
    mrsh[n*68 + dd] = fmaxf(mv * (1.f + LAMf*SA) + LAMf*Bsh[dd], 0.f);
  }
  __syncthreads();

  // fragments (single 16-node tile)
  bf16x8 mrf[2], hf[2];
  {
    const float* mp = mrsh + m15*68 + kq*8;
    const float* hp = h + (size_t)(nb + m15)*64 + kq*8;
    #pragma unroll
    for (int ks = 0; ks < 2; ++ks) {
      mrf[ks] = pack8v(*(const f32x4*)(mp + ks*32), *(const f32x4*)(mp + ks*32 + 4));
      hf[ks]  = pack8v(*(const f32x4*)(hp + ks*32), *(const f32x4*)(hp + ks*32 + 4));
    }
  }
  const int d = wave*16 + m15;
  f32x4 gi[3], gh[3];
  #pragma unroll
  for (int p = 0; p < 3; ++p) {
    int j = p*64 + d;
    bf16x8 bi0 = *(const bf16x8*)(gwihB + j*64 + kq*8);
    bf16x8 bi1 = *(const bf16x8*)(gwihB + j*64 + 32 + kq*8);
    bf16x8 bh0 = *(const bf16x8*)(gwhhB + j*64 + kq*8);
    bf16x8 bh1 = *(const bf16x8*)(gwhhB + j*64 + 32 + kq*8);
    f32x4 a = __builtin_amdgcn_mfma_f32_16x16x32_bf16(mrf[0], bi0, zero4, 0, 0, 0);
    gi[p] = __builtin_amdgcn_mfma_f32_16x16x32_bf16(mrf[1], bi1, a, 0, 0, 0);
    f32x4 b = __builtin_amdgcn_mfma_f32_16x16x32_bf16(hf[0], bh0, zero4, 0, 0, 0);
    gh[p] = __builtin_amdgcn_mfma_f32_16x16x32_bf16(hf[1], bh1, b, 0, 0, 0);
  }
  float bir = bih[d],      bhr = bhh[d];
  float biz = bih[64 + d], bhz = bhh[64 + d];
  float bin = bih[128 + d], bhn = bhh[128 + d];
  __syncthreads();   // all h-fragment reads done before any h write
  #pragma unroll
  for (int r = 0; r < 4; ++r) {
    int node = nb + kq*4 + r;
    float rr = sigm(gi[0][r] + bir + gh[0][r] + bhr);
    float z  = sigm(gi[1][r] + biz + gh[1][r] + bhz);
    float nn = tanhf(gi[2][r] + bin + rr * (gh[2][r] + bhn));
    float hv = h[node*64 + d];
    float hn = (1.f - z) * nn + z * hv;
    h[node*64 + d] = hn;
    out[node*64 + d] = hn + out[node*64 + d];
  }
}

// ---------------- global mean pool (atomic) ----------------
__global__ void k_pool(const float* __restrict__ out, const int* __restrict__ batch,
                       float* __restrict__ pooled, float* __restrict__ pcnt) {
  int idx = blockIdx.x * 256 + threadIdx.x;
  int n = idx >> 6, d = idx & 63;
  int b = batch[n];
  atomicAdd(&pooled[b*64 + d], out[idx]);
  if (d == 0) atomicAdd(&pcnt[b], 1.f);
}

// ---------------- post FC + output ----------------
__global__ void k_final(const float* __restrict__ pooled, const float* __restrict__ pcnt,
                        const float* __restrict__ postW, const float* __restrict__ postb,
                        const float* __restrict__ outW, const float* __restrict__ outb,
                        float* __restrict__ y) {
  int b = blockIdx.x, d = threadIdx.x;
  __shared__ float pl[64];
  float c = fmaxf(pcnt[b], 1.f);
  pl[d] = pooled[b*64 + d] / c;
  __syncthreads();
  float acc = postb[d];
  #pragma unroll 8
  for (int k = 0; k < 64; ++k) acc += pl[k] * postW[k*64 + d];
  acc = fmaxf(acc, 0.f);
  float v = acc * outW[d];
  #pragma unroll
  for (int off = 32; off > 0; off >>= 1) v += __shfl_down(v, off, 64);
  if (d == 0) y[b] = v + outb[0];
}

extern "C" void kernel_launch(void* const* d_in, const int* in_sizes, int n_in,
                              void* d_out, int out_size, void* d_ws, size_t ws_size,
                              hipStream_t stream) {
  (void)in_sizes; (void)n_in; (void)out_size; (void)ws_size;
  const float* x        = (const float*)d_in[0];
  const float* edge_attr= (const float*)d_in[1];
  const float* preW     = (const float*)d_in[2];
  const float* preb     = (const float*)d_in[3];
  const float* ew1      = (const float*)d_in[4];
  const float* eb1      = (const float*)d_in[5];
  const float* ew2      = (const float*)d_in[6];
  const float* eb2      = (const float*)d_in[7];
  const float* rootw    = (const float*)d_in[8];
  const float* rootb    = (const float*)d_in[9];
  const float* gwih     = (const float*)d_in[10];
  const float* gwhh     = (const float*)d_in[11];
  const float* gbih     = (const float*)d_in[12];
  const float* gbhh     = (const float*)d_in[13];
  const float* gnlin    = (const float*)d_in[14];
  const float* gngamma  = (const float*)d_in[15];
  const float* gnbeta   = (const float*)d_in[16];
  const float* postW    = (const float*)d_in[17];
  const float* postb    = (const float*)d_in[18];
  const float* outW     = (const float*)d_in[19];
  const float* outb     = (const float*)d_in[20];
  const int*   eidx     = (const int*)d_in[21];
  const int*   batch    = (const int*)d_in[22];
  const int* src = eidx;
  const int* dst = eidx + Ee;
  float* y = (float*)d_out;

  float* ws     = (float*)d_ws;
  float* out    = ws;                     // N*64
  float* hbuf   = out    + Nn*64;
  float* mbuf   = hbuf   + Nn*64;
  float* sbuf   = mbuf   + Nn*64;         // N*16
  float* agg    = sbuf   + Nn*16;         // N*64
  float* stats  = agg    + Nn*64;         // 2048 (contiguous with agg: 1 memset)
  float* cnt    = stats  + 2048;          // N
  float* pooled = cnt    + Nn;            // N (>= B*64)
  float* pcnt   = pooled + Nn;            // 64
  float* bfbase = pcnt   + 64;
  short* w1T    = (short*)bfbase;         // 3*4096
  short* b2T    = w1T    + 3*4096;
  short* w2T    = b2T    + 3*4096;        // 3*262144
  short* rootwT = w2T    + 3*262144;      // 3*4096
  short* gwihB  = rootwT + 3*4096;        // 3*12288
  short* gwhhB  = gwihB  + 3*12288;       // 3*12288
  short* preWT  = gwhhB  + 3*12288;       // 8192

  hipMemsetAsync(cnt, 0, (Nn + Nn + 64)*sizeof(float), stream);

  k_prep<<<3072, 256, 0, stream>>>(ew1, ew2, eb2, rootw, gwih, gwhh, preW,
                                   w1T, b2T, w2T, rootwT, gwihB, gwhhB, preWT);
  k_tkl<<<1, 256, 0, stream>>>(preW, preb, postW, postb, outW, outb, y);
  k_count<<<Ee/256, 256, 0, stream>>>(dst, cnt);
  k_pre<<<Nn/16, 256, 0, stream>>>(x, preWT, preb, out, hbuf);

  for (int i = 0; i < 3; ++i) {
    hipMemsetAsync(agg, 0, (Nn*64 + 2048)*sizeof(float), stream);
    k_msg<<<Ee/128, 512, 0, stream>>>(out, edge_attr,
                                     w1T + i*4096, eb1 + i*64,
                                     w2T + i*262144, b2T + i*4096,
                                     src, dst, agg);
    k_m_fused<<<Nn/16, 256, 0, stream>>>(agg, cnt, out, rootwT + i*4096,
                                         rootb + i*64, gnlin + i*640, mbuf, sbuf, stats);
    k_gru<<<Nn/16, 256, 0, stream>>>(mbuf, sbuf, stats, gngamma + i*640, gnbeta + i*640,
                                     gwihB + i*12288, gwhhB + i*12288,
                                     gbih + i*192, gbhh + i*192, hbuf, out);
  }

  k_pool<<<Nn*64/256, 256, 0, stream>>>(out, batch, pooled, pcnt);
  k_final<<<Bb, 64, 0, stream>>>(pooled, pcnt, postW, postb, outW, outb, y);
}